// Round 9
// baseline (138.348 us; speedup 1.0000x reference)
//
#include <hip/hip_runtime.h>

#define HW 512
#define PITCH 408   // d1 LDS row pitch (dwords); off(c) = 3c + (c>>3), max 402 < 408

__device__ __forceinline__ float prelu(float x, float a) { return x >= 0.f ? x : a * x; }

// Single fused kernel. Grid (4,32,8) = 1024 blocks x 256 threads = EXACTLY 4 blocks/CU
// on 256 CUs; __launch_bounds__(256,4) caps VGPR<=128 and LDS use is 27.7KB<=40KB, so
// all blocks are co-resident and the per-batch spin below cannot deadlock.
// Tile: 16 rows x 128 cols, 8 px/thread, s held in registers across the sync.
__global__ __launch_bounds__(256, 4) void fused_spin(
    const float* __restrict__ in1, const float* __restrict__ in2, const float* __restrict__ in3,
    const float* __restrict__ Wd, const float* __restrict__ bd, const float* __restrict__ ad,
    const float* __restrict__ Wu, const float* __restrict__ bu, const float* __restrict__ au,
    const float* __restrict__ Wc, const float* __restrict__ bc, const float* __restrict__ ag,
    int* __restrict__ cnt, float* __restrict__ partials, float* __restrict__ out)
{
    __shared__ float d1[17 * PITCH];
    __shared__ float red[4][3];
    __shared__ float ybuf[3];

    const int tid   = threadIdx.x;
    const int bx    = blockIdx.x;      // 0..3  col tile (128 px)
    const int by    = blockIdx.y;      // 0..31 row tile (16 px)
    const int batch = blockIdx.z;      // 0..7
    const int h0    = by * 16;
    const int w0b   = bx * 128;

    float wd[9], wu[9];
    #pragma unroll
    for (int k = 0; k < 9; k++) { wd[k] = Wd[k]; wu[k] = Wu[k]; }
    const float bd0 = bd[0], bd1 = bd[1], bd2 = bd[2];
    const float ad0 = ad[0], ad1 = ad[1], ad2 = ad[2];
    const float bu0 = bu[0], bu1 = bu[1], bu2 = bu[2];
    const float au0 = au[0], au1 = au[1], au2 = au[2];
    const float cu0 = prelu(bu0, au0), cu1 = prelu(bu1, au1), cu2 = prelu(bu2, au2);

    // ---- Phase A: stage d1 (17 rows x 129 cols). Task (r,g): 13 aligned float4
    // loads (branch-free, row clamped), compute d1 cols 8g..8g+7 (+col 128 for g=15).
    #pragma unroll
    for (int step = 0; step < 2; ++step) {
        const int r = step ? 16 : (tid >> 4);
        const int g = step ? tid : (tid & 15);
        if (step == 0 || tid < 16) {
            const int gh  = h0 + r;
            const int ghc = gh < HW ? gh : (HW - 1);
            const float* rb = in1 + ((size_t)(batch * 1024 + 2 * ghc)) * 3072;
            const int px0 = 2 * w0b + 16 * g;
            const float4* lp = reinterpret_cast<const float4*>(rb + (size_t)px0 * 3);
            float arr[52];
            #pragma unroll
            for (int k = 0; k < 13; ++k)
                *reinterpret_cast<float4*>(&arr[4 * k]) = lp[k];   // back-to-back issue

            const bool rowOOR = (gh >= HW);
            float* q = d1 + r * PITCH + 25 * g;   // off(8g+j) = 25g + 3j
            #pragma unroll
            for (int j = 0; j < 8; ++j) {
                const float x0 = arr[6 * j], x1 = arr[6 * j + 1], x2 = arr[6 * j + 2];
                float v0 = prelu(x0 * wd[0] + x1 * wd[3] + x2 * wd[6] + bd0, ad0);
                float v1 = prelu(x0 * wd[1] + x1 * wd[4] + x2 * wd[7] + bd1, ad1);
                float v2 = prelu(x0 * wd[2] + x1 * wd[5] + x2 * wd[8] + bd2, ad2);
                q[3 * j + 0] = rowOOR ? -INFINITY : v0;
                q[3 * j + 1] = rowOOR ? -INFINITY : v1;
                q[3 * j + 2] = rowOOR ? -INFINITY : v2;
            }
            if (g == 15) {   // halo col 128 <- px0+16 = arr[48..50]; off(128)=400
                const float x0 = arr[48], x1 = arr[49], x2 = arr[50];
                float v0 = prelu(x0 * wd[0] + x1 * wd[3] + x2 * wd[6] + bd0, ad0);
                float v1 = prelu(x0 * wd[1] + x1 * wd[4] + x2 * wd[7] + bd1, ad1);
                float v2 = prelu(x0 * wd[2] + x1 * wd[5] + x2 * wd[8] + bd2, ad2);
                const bool oor = rowOOR || (w0b + 128 >= HW);
                float* qh = d1 + r * PITCH + 400;
                qh[0] = oor ? -INFINITY : v0;
                qh[1] = oor ? -INFINITY : v1;
                qh[2] = oor ? -INFINITY : v2;
            }
        }
    }
    __syncthreads();

    // ---- Phase B: 8 consecutive px per thread ----
    const int r  = tid >> 4;
    const int g  = tid & 15;
    const int h  = h0 + r;
    const int w0 = w0b + g * 8;

    const float* in2p = in2 + ((size_t)((batch * HW + h) * HW + w0)) * 3;
    float i2v[24];
    #pragma unroll
    for (int k = 0; k < 6; ++k)
        *reinterpret_cast<float4*>(&i2v[4 * k]) = reinterpret_cast<const float4*>(in2p)[k];

    const int he   = h + (h & 1);
    const bool rOK = he < HW;
    const int hr3  = rOK ? (he >> 1) : 255;
    const int w3   = w0 >> 1;
    float ur[15];
    #pragma unroll
    for (int k = 0; k < 5; ++k) {
        const int wc = (w3 + k < 256) ? (w3 + k) : 255;
        const float* p = in3 + ((size_t)(batch * 256 + hr3) * 256 + wc) * 3;
        ur[3 * k + 0] = p[0]; ur[3 * k + 1] = p[1]; ur[3 * k + 2] = p[2];
    }
    float ud[5][3];
    #pragma unroll
    for (int k = 0; k < 5; ++k) {
        const bool ok = rOK && (w3 + k < 256);
        const float x0 = ur[3 * k], x1 = ur[3 * k + 1], x2 = ur[3 * k + 2];
        const float u0 = prelu(x0 * wu[0] + x1 * wu[3] + x2 * wu[6] + bu0, au0);
        const float u1 = prelu(x0 * wu[1] + x1 * wu[4] + x2 * wu[7] + bu1, au1);
        const float u2 = prelu(x0 * wu[2] + x1 * wu[5] + x2 * wu[8] + bu2, au2);
        ud[k][0] = ok ? fmaxf(cu0, u0) : cu0;
        ud[k][1] = ok ? fmaxf(cu1, u1) : cu1;
        ud[k][2] = ok ? fmaxf(cu2, u2) : cu2;
    }

    // rolling 2x2 maxpool over d1 rows r,r+1; off(8g+j) = 25g+3j, off(8g+8)=25g+25
    const int baseA = r * PITCH + 25 * g;
    const int baseB = baseA + PITCH;
    float pA0 = d1[baseA + 0], pA1 = d1[baseA + 1], pA2 = d1[baseA + 2];
    float pB0 = d1[baseB + 0], pB1 = d1[baseB + 1], pB2 = d1[baseB + 2];

    float s[8][3];
    #pragma unroll
    for (int j = 0; j < 8; ++j) {
        const int o = 3 * (j + 1) + ((j + 1) >> 3);
        const float cA0 = d1[baseA + o], cA1 = d1[baseA + o + 1], cA2 = d1[baseA + o + 2];
        const float cB0 = d1[baseB + o], cB1 = d1[baseB + o + 1], cB2 = d1[baseB + o + 2];
        const int uk = (j + 1) >> 1;
        s[j][0] = fmaxf(fmaxf(pA0, cA0), fmaxf(pB0, cB0)) + i2v[3 * j + 0] + ud[uk][0];
        s[j][1] = fmaxf(fmaxf(pA1, cA1), fmaxf(pB1, cB1)) + i2v[3 * j + 1] + ud[uk][1];
        s[j][2] = fmaxf(fmaxf(pA2, cA2), fmaxf(pB2, cB2)) + i2v[3 * j + 2] + ud[uk][2];
        pA0 = cA0; pA1 = cA1; pA2 = cA2;
        pB0 = cB0; pB1 = cB1; pB2 = cB2;
    }

    // ---- block partial + device-scope publish + per-batch spin ----
    float sum0 = 0.f, sum1 = 0.f, sum2 = 0.f;
    #pragma unroll
    for (int j = 0; j < 8; ++j) { sum0 += s[j][0]; sum1 += s[j][1]; sum2 += s[j][2]; }
    #pragma unroll
    for (int off = 32; off > 0; off >>= 1) {
        sum0 += __shfl_down(sum0, off);
        sum1 += __shfl_down(sum1, off);
        sum2 += __shfl_down(sum2, off);
    }
    if ((tid & 63) == 0) { red[tid >> 6][0] = sum0; red[tid >> 6][1] = sum1; red[tid >> 6][2] = sum2; }
    __syncthreads();
    if (tid == 0) {
        const int slot = batch * 128 + by * 4 + bx;
        const float t0 = red[0][0] + red[1][0] + red[2][0] + red[3][0];
        const float t1 = red[0][1] + red[1][1] + red[2][1] + red[3][1];
        const float t2 = red[0][2] + red[1][2] + red[2][2] + red[3][2];
        __hip_atomic_store(&partials[slot * 3 + 0], t0, __ATOMIC_RELAXED, __HIP_MEMORY_SCOPE_AGENT);
        __hip_atomic_store(&partials[slot * 3 + 1], t1, __ATOMIC_RELAXED, __HIP_MEMORY_SCOPE_AGENT);
        __hip_atomic_store(&partials[slot * 3 + 2], t2, __ATOMIC_RELAXED, __HIP_MEMORY_SCOPE_AGENT);
        __hip_atomic_fetch_add(&cnt[batch], 1, __ATOMIC_RELEASE, __HIP_MEMORY_SCOPE_AGENT);
        while (__hip_atomic_load(&cnt[batch], __ATOMIC_ACQUIRE, __HIP_MEMORY_SCOPE_AGENT) < 128)
            __builtin_amdgcn_s_sleep(2);
    }
    __syncthreads();   // all threads see completed partials

    // ---- gate: wave 0, fixed tree (identical in every block -> deterministic) ----
    if (tid < 64) {
        const float* pw = partials + batch * 128 * 3;
        float g0, g1, g2;
        {
            const int i0 = tid * 3, i1 = (tid + 64) * 3;
            g0 = __hip_atomic_load(&pw[i0 + 0], __ATOMIC_RELAXED, __HIP_MEMORY_SCOPE_AGENT)
               + __hip_atomic_load(&pw[i1 + 0], __ATOMIC_RELAXED, __HIP_MEMORY_SCOPE_AGENT);
            g1 = __hip_atomic_load(&pw[i0 + 1], __ATOMIC_RELAXED, __HIP_MEMORY_SCOPE_AGENT)
               + __hip_atomic_load(&pw[i1 + 1], __ATOMIC_RELAXED, __HIP_MEMORY_SCOPE_AGENT);
            g2 = __hip_atomic_load(&pw[i0 + 2], __ATOMIC_RELAXED, __HIP_MEMORY_SCOPE_AGENT)
               + __hip_atomic_load(&pw[i1 + 2], __ATOMIC_RELAXED, __HIP_MEMORY_SCOPE_AGENT);
        }
        #pragma unroll
        for (int off = 32; off > 0; off >>= 1) {
            g0 += __shfl_down(g0, off);
            g1 += __shfl_down(g1, off);
            g2 += __shfl_down(g2, off);
        }
        if (tid == 0) {
            const float inv_n = 1.f / (float)(HW * HW);
            g0 *= inv_n; g1 *= inv_n; g2 *= inv_n;
            const float x0 = prelu(g0 * Wc[0] + g1 * Wc[3] + g2 * Wc[6] + bc[0], ag[0]);
            const float x1 = prelu(g0 * Wc[1] + g1 * Wc[4] + g2 * Wc[7] + bc[1], ag[1]);
            const float x2 = prelu(g0 * Wc[2] + g1 * Wc[5] + g2 * Wc[8] + bc[2], ag[2]);
            const float q0 = x0 * Wc[0] + x1 * Wc[3] + x2 * Wc[6] + bc[0];
            const float q1 = x0 * Wc[1] + x1 * Wc[4] + x2 * Wc[7] + bc[1];
            const float q2 = x0 * Wc[2] + x1 * Wc[5] + x2 * Wc[8] + bc[2];
            const float m  = fmaxf(q0, fmaxf(q1, q2));
            const float e0 = expf(q0 - m), e1 = expf(q1 - m), e2 = expf(q2 - m);
            const float inv = 1.f / (e0 + e1 + e2);
            ybuf[0] = e0 * inv; ybuf[1] = e1 * inv; ybuf[2] = e2 * inv;
        }
    }
    __syncthreads();
    const float ym[3] = { ybuf[0], ybuf[1], ybuf[2] };

    // ---- scale register-resident s, write 6x float4 ----
    float* outp = out + ((size_t)((batch * HW + h) * HW + w0)) * 3;
    #pragma unroll
    for (int k = 0; k < 6; ++k) {
        float4 v;
        v.x = s[(4 * k + 0) / 3][(4 * k + 0) % 3] * ym[(4 * k + 0) % 3];
        v.y = s[(4 * k + 1) / 3][(4 * k + 1) % 3] * ym[(4 * k + 1) % 3];
        v.z = s[(4 * k + 2) / 3][(4 * k + 2) % 3] * ym[(4 * k + 2) % 3];
        v.w = s[(4 * k + 3) / 3][(4 * k + 3) % 3] * ym[(4 * k + 3) % 3];
        reinterpret_cast<float4*>(outp)[k] = v;
    }
}

extern "C" void kernel_launch(void* const* d_in, const int* in_sizes, int n_in,
                              void* d_out, int out_size, void* d_ws, size_t ws_size,
                              hipStream_t stream)
{
    const float* in1 = (const float*)d_in[0];
    const float* in2 = (const float*)d_in[1];
    const float* in3 = (const float*)d_in[2];
    const float* Wd  = (const float*)d_in[3];
    const float* bd  = (const float*)d_in[4];
    const float* ad  = (const float*)d_in[5];
    const float* Wu  = (const float*)d_in[6];
    const float* bu  = (const float*)d_in[7];
    const float* au  = (const float*)d_in[8];
    const float* Wc  = (const float*)d_in[9];
    const float* bc  = (const float*)d_in[10];
    const float* ag  = (const float*)d_in[11];
    float* out = (float*)d_out;

    int*   cnt      = (int*)d_ws;                       // 8 counters
    float* partials = (float*)((char*)d_ws + 64);       // 1024*3 floats

    hipMemsetAsync(d_ws, 0, 64, stream);                // zero counters each call (capturable)
    fused_spin<<<dim3(4, 32, 8), 256, 0, stream>>>(in1, in2, in3, Wd, bd, ad, Wu, bu, au,
                                                   Wc, bc, ag, cnt, partials, out);
}

// Round 10
// 126.148 us; speedup vs baseline: 1.0967x; 1.0967x over previous
//
#include <hip/hip_runtime.h>

#define HW 512
#define PITCH 408   // d1 LDS row pitch (dwords); off(c) = 3c + (c>>3), max 402 < 408

__device__ __forceinline__ float prelu(float x, float a) { return x >= 0.f ? x : a * x; }

// Single fused kernel, leader-elect sync (no grid-wide barrier, no hot spin).
// Grid (4,32,8) = 1024 blocks x 256 threads = 4 blocks/CU on 256 CUs, co-resident
// (LDS 28KB, VGPR<=128 via __launch_bounds__(256,4)) -> flag will always be set.
// Tile: 16 rows x 128 cols, 8 px/thread, s held in registers across the sync.
__global__ __launch_bounds__(256, 4) void fused_leader(
    const float* __restrict__ in1, const float* __restrict__ in2, const float* __restrict__ in3,
    const float* __restrict__ Wd, const float* __restrict__ bd, const float* __restrict__ ad,
    const float* __restrict__ Wu, const float* __restrict__ bu, const float* __restrict__ au,
    const float* __restrict__ Wc, const float* __restrict__ bc, const float* __restrict__ ag,
    int* __restrict__ cnt, int* __restrict__ flag, float* __restrict__ partials,
    float* __restrict__ yG, float* __restrict__ out)
{
    __shared__ float d1[17 * PITCH];
    __shared__ float red[4][3];
    __shared__ float ybuf[3];
    __shared__ int   leader_f;

    const int tid   = threadIdx.x;
    const int bx    = blockIdx.x;      // 0..3  col tile (128 px)
    const int by    = blockIdx.y;      // 0..31 row tile (16 px)
    const int batch = blockIdx.z;      // 0..7
    const int h0    = by * 16;
    const int w0b   = bx * 128;

    float wd[9], wu[9];
    #pragma unroll
    for (int k = 0; k < 9; k++) { wd[k] = Wd[k]; wu[k] = Wu[k]; }
    const float bd0 = bd[0], bd1 = bd[1], bd2 = bd[2];
    const float ad0 = ad[0], ad1 = ad[1], ad2 = ad[2];
    const float bu0 = bu[0], bu1 = bu[1], bu2 = bu[2];
    const float au0 = au[0], au1 = au[1], au2 = au[2];
    const float cu0 = prelu(bu0, au0), cu1 = prelu(bu1, au1), cu2 = prelu(bu2, au2);

    // ---- Phase A: stage d1 (17 rows x 129 cols), branch-free aligned float4 loads ----
    #pragma unroll
    for (int step = 0; step < 2; ++step) {
        const int r = step ? 16 : (tid >> 4);
        const int g = step ? tid : (tid & 15);
        if (step == 0 || tid < 16) {
            const int gh  = h0 + r;
            const int ghc = gh < HW ? gh : (HW - 1);
            const float* rb = in1 + ((size_t)(batch * 1024 + 2 * ghc)) * 3072;
            const int px0 = 2 * w0b + 16 * g;
            const float4* lp = reinterpret_cast<const float4*>(rb + (size_t)px0 * 3);
            float arr[52];
            #pragma unroll
            for (int k = 0; k < 13; ++k)
                *reinterpret_cast<float4*>(&arr[4 * k]) = lp[k];

            const bool rowOOR = (gh >= HW);
            float* q = d1 + r * PITCH + 25 * g;   // off(8g+j) = 25g + 3j
            #pragma unroll
            for (int j = 0; j < 8; ++j) {
                const float x0 = arr[6 * j], x1 = arr[6 * j + 1], x2 = arr[6 * j + 2];
                float v0 = prelu(x0 * wd[0] + x1 * wd[3] + x2 * wd[6] + bd0, ad0);
                float v1 = prelu(x0 * wd[1] + x1 * wd[4] + x2 * wd[7] + bd1, ad1);
                float v2 = prelu(x0 * wd[2] + x1 * wd[5] + x2 * wd[8] + bd2, ad2);
                q[3 * j + 0] = rowOOR ? -INFINITY : v0;
                q[3 * j + 1] = rowOOR ? -INFINITY : v1;
                q[3 * j + 2] = rowOOR ? -INFINITY : v2;
            }
            if (g == 15) {   // halo col 128; off(128)=400
                const float x0 = arr[48], x1 = arr[49], x2 = arr[50];
                float v0 = prelu(x0 * wd[0] + x1 * wd[3] + x2 * wd[6] + bd0, ad0);
                float v1 = prelu(x0 * wd[1] + x1 * wd[4] + x2 * wd[7] + bd1, ad1);
                float v2 = prelu(x0 * wd[2] + x1 * wd[5] + x2 * wd[8] + bd2, ad2);
                const bool oor = rowOOR || (w0b + 128 >= HW);
                float* qh = d1 + r * PITCH + 400;
                qh[0] = oor ? -INFINITY : v0;
                qh[1] = oor ? -INFINITY : v1;
                qh[2] = oor ? -INFINITY : v2;
            }
        }
    }
    __syncthreads();

    // ---- Phase B: 8 consecutive px per thread ----
    const int r  = tid >> 4;
    const int g  = tid & 15;
    const int h  = h0 + r;
    const int w0 = w0b + g * 8;

    const float* in2p = in2 + ((size_t)((batch * HW + h) * HW + w0)) * 3;
    float i2v[24];
    #pragma unroll
    for (int k = 0; k < 6; ++k)
        *reinterpret_cast<float4*>(&i2v[4 * k]) = reinterpret_cast<const float4*>(in2p)[k];

    const int he   = h + (h & 1);
    const bool rOK = he < HW;
    const int hr3  = rOK ? (he >> 1) : 255;
    const int w3   = w0 >> 1;
    float ur[15];
    #pragma unroll
    for (int k = 0; k < 5; ++k) {
        const int wc = (w3 + k < 256) ? (w3 + k) : 255;
        const float* p = in3 + ((size_t)(batch * 256 + hr3) * 256 + wc) * 3;
        ur[3 * k + 0] = p[0]; ur[3 * k + 1] = p[1]; ur[3 * k + 2] = p[2];
    }
    float ud[5][3];
    #pragma unroll
    for (int k = 0; k < 5; ++k) {
        const bool ok = rOK && (w3 + k < 256);
        const float x0 = ur[3 * k], x1 = ur[3 * k + 1], x2 = ur[3 * k + 2];
        const float u0 = prelu(x0 * wu[0] + x1 * wu[3] + x2 * wu[6] + bu0, au0);
        const float u1 = prelu(x0 * wu[1] + x1 * wu[4] + x2 * wu[7] + bu1, au1);
        const float u2 = prelu(x0 * wu[2] + x1 * wu[5] + x2 * wu[8] + bu2, au2);
        ud[k][0] = ok ? fmaxf(cu0, u0) : cu0;
        ud[k][1] = ok ? fmaxf(cu1, u1) : cu1;
        ud[k][2] = ok ? fmaxf(cu2, u2) : cu2;
    }

    const int baseA = r * PITCH + 25 * g;
    const int baseB = baseA + PITCH;
    float pA0 = d1[baseA + 0], pA1 = d1[baseA + 1], pA2 = d1[baseA + 2];
    float pB0 = d1[baseB + 0], pB1 = d1[baseB + 1], pB2 = d1[baseB + 2];

    float s[8][3];
    #pragma unroll
    for (int j = 0; j < 8; ++j) {
        const int o = 3 * (j + 1) + ((j + 1) >> 3);
        const float cA0 = d1[baseA + o], cA1 = d1[baseA + o + 1], cA2 = d1[baseA + o + 2];
        const float cB0 = d1[baseB + o], cB1 = d1[baseB + o + 1], cB2 = d1[baseB + o + 2];
        const int uk = (j + 1) >> 1;
        s[j][0] = fmaxf(fmaxf(pA0, cA0), fmaxf(pB0, cB0)) + i2v[3 * j + 0] + ud[uk][0];
        s[j][1] = fmaxf(fmaxf(pA1, cA1), fmaxf(pB1, cB1)) + i2v[3 * j + 1] + ud[uk][1];
        s[j][2] = fmaxf(fmaxf(pA2, cA2), fmaxf(pB2, cB2)) + i2v[3 * j + 2] + ud[uk][2];
        pA0 = cA0; pA1 = cA1; pA2 = cA2;
        pB0 = cB0; pB1 = cB1; pB2 = cB2;
    }

    // ---- block partial + publish + leader election ----
    float sum0 = 0.f, sum1 = 0.f, sum2 = 0.f;
    #pragma unroll
    for (int j = 0; j < 8; ++j) { sum0 += s[j][0]; sum1 += s[j][1]; sum2 += s[j][2]; }
    #pragma unroll
    for (int off = 32; off > 0; off >>= 1) {
        sum0 += __shfl_down(sum0, off);
        sum1 += __shfl_down(sum1, off);
        sum2 += __shfl_down(sum2, off);
    }
    if ((tid & 63) == 0) { red[tid >> 6][0] = sum0; red[tid >> 6][1] = sum1; red[tid >> 6][2] = sum2; }
    __syncthreads();
    if (tid == 0) {
        const int slot = batch * 128 + by * 4 + bx;
        const float t0 = red[0][0] + red[1][0] + red[2][0] + red[3][0];
        const float t1 = red[0][1] + red[1][1] + red[2][1] + red[3][1];
        const float t2 = red[0][2] + red[1][2] + red[2][2] + red[3][2];
        __hip_atomic_store(&partials[slot * 3 + 0], t0, __ATOMIC_RELAXED, __HIP_MEMORY_SCOPE_AGENT);
        __hip_atomic_store(&partials[slot * 3 + 1], t1, __ATOMIC_RELAXED, __HIP_MEMORY_SCOPE_AGENT);
        __hip_atomic_store(&partials[slot * 3 + 2], t2, __ATOMIC_RELAXED, __HIP_MEMORY_SCOPE_AGENT);
        const int old = __hip_atomic_fetch_add(&cnt[batch], 1, __ATOMIC_ACQ_REL, __HIP_MEMORY_SCOPE_AGENT);
        leader_f = (old == 127);
    }
    __syncthreads();

    if (leader_f) {
        // leader: wave 0 reduces all 128 partials (fixed tree -> deterministic y)
        if (tid < 64) {
            const float* pw = partials + batch * 128 * 3;
            const int i0 = tid * 3, i1 = (tid + 64) * 3;
            float g0 = __hip_atomic_load(&pw[i0 + 0], __ATOMIC_RELAXED, __HIP_MEMORY_SCOPE_AGENT)
                     + __hip_atomic_load(&pw[i1 + 0], __ATOMIC_RELAXED, __HIP_MEMORY_SCOPE_AGENT);
            float g1 = __hip_atomic_load(&pw[i0 + 1], __ATOMIC_RELAXED, __HIP_MEMORY_SCOPE_AGENT)
                     + __hip_atomic_load(&pw[i1 + 1], __ATOMIC_RELAXED, __HIP_MEMORY_SCOPE_AGENT);
            float g2 = __hip_atomic_load(&pw[i0 + 2], __ATOMIC_RELAXED, __HIP_MEMORY_SCOPE_AGENT)
                     + __hip_atomic_load(&pw[i1 + 2], __ATOMIC_RELAXED, __HIP_MEMORY_SCOPE_AGENT);
            #pragma unroll
            for (int off = 32; off > 0; off >>= 1) {
                g0 += __shfl_down(g0, off);
                g1 += __shfl_down(g1, off);
                g2 += __shfl_down(g2, off);
            }
            if (tid == 0) {
                const float inv_n = 1.f / (float)(HW * HW);
                g0 *= inv_n; g1 *= inv_n; g2 *= inv_n;
                const float x0 = prelu(g0 * Wc[0] + g1 * Wc[3] + g2 * Wc[6] + bc[0], ag[0]);
                const float x1 = prelu(g0 * Wc[1] + g1 * Wc[4] + g2 * Wc[7] + bc[1], ag[1]);
                const float x2 = prelu(g0 * Wc[2] + g1 * Wc[5] + g2 * Wc[8] + bc[2], ag[2]);
                const float q0 = x0 * Wc[0] + x1 * Wc[3] + x2 * Wc[6] + bc[0];
                const float q1 = x0 * Wc[1] + x1 * Wc[4] + x2 * Wc[7] + bc[1];
                const float q2 = x0 * Wc[2] + x1 * Wc[5] + x2 * Wc[8] + bc[2];
                const float m  = fmaxf(q0, fmaxf(q1, q2));
                const float e0 = expf(q0 - m), e1 = expf(q1 - m), e2 = expf(q2 - m);
                const float inv = 1.f / (e0 + e1 + e2);
                const float y0 = e0 * inv, y1 = e1 * inv, y2 = e2 * inv;
                ybuf[0] = y0; ybuf[1] = y1; ybuf[2] = y2;
                __hip_atomic_store(&yG[batch * 3 + 0], y0, __ATOMIC_RELAXED, __HIP_MEMORY_SCOPE_AGENT);
                __hip_atomic_store(&yG[batch * 3 + 1], y1, __ATOMIC_RELAXED, __HIP_MEMORY_SCOPE_AGENT);
                __hip_atomic_store(&yG[batch * 3 + 2], y2, __ATOMIC_RELAXED, __HIP_MEMORY_SCOPE_AGENT);
                __hip_atomic_store(&flag[batch], 1, __ATOMIC_RELEASE, __HIP_MEMORY_SCOPE_AGENT);
            }
        }
    } else {
        // non-leader: ONE lane cold-polls the flag (~0.85us between polls)
        if (tid == 0) {
            while (__hip_atomic_load(&flag[batch], __ATOMIC_RELAXED, __HIP_MEMORY_SCOPE_AGENT) == 0)
                __builtin_amdgcn_s_sleep(32);
            (void)__hip_atomic_load(&flag[batch], __ATOMIC_ACQUIRE, __HIP_MEMORY_SCOPE_AGENT);
            ybuf[0] = __hip_atomic_load(&yG[batch * 3 + 0], __ATOMIC_RELAXED, __HIP_MEMORY_SCOPE_AGENT);
            ybuf[1] = __hip_atomic_load(&yG[batch * 3 + 1], __ATOMIC_RELAXED, __HIP_MEMORY_SCOPE_AGENT);
            ybuf[2] = __hip_atomic_load(&yG[batch * 3 + 2], __ATOMIC_RELAXED, __HIP_MEMORY_SCOPE_AGENT);
        }
    }
    __syncthreads();
    const float ym[3] = { ybuf[0], ybuf[1], ybuf[2] };

    // ---- scale register-resident s, write 6x float4 ----
    float* outp = out + ((size_t)((batch * HW + h) * HW + w0)) * 3;
    #pragma unroll
    for (int k = 0; k < 6; ++k) {
        float4 v;
        v.x = s[(4 * k + 0) / 3][(4 * k + 0) % 3] * ym[(4 * k + 0) % 3];
        v.y = s[(4 * k + 1) / 3][(4 * k + 1) % 3] * ym[(4 * k + 1) % 3];
        v.z = s[(4 * k + 2) / 3][(4 * k + 2) % 3] * ym[(4 * k + 2) % 3];
        v.w = s[(4 * k + 3) / 3][(4 * k + 3) % 3] * ym[(4 * k + 3) % 3];
        reinterpret_cast<float4*>(outp)[k] = v;
    }
}

extern "C" void kernel_launch(void* const* d_in, const int* in_sizes, int n_in,
                              void* d_out, int out_size, void* d_ws, size_t ws_size,
                              hipStream_t stream)
{
    const float* in1 = (const float*)d_in[0];
    const float* in2 = (const float*)d_in[1];
    const float* in3 = (const float*)d_in[2];
    const float* Wd  = (const float*)d_in[3];
    const float* bd  = (const float*)d_in[4];
    const float* ad  = (const float*)d_in[5];
    const float* Wu  = (const float*)d_in[6];
    const float* bu  = (const float*)d_in[7];
    const float* au  = (const float*)d_in[8];
    const float* Wc  = (const float*)d_in[9];
    const float* bc  = (const float*)d_in[10];
    const float* ag  = (const float*)d_in[11];
    float* out = (float*)d_out;

    int*   cnt      = (int*)d_ws;                        // 8 ints
    int*   flag     = (int*)((char*)d_ws + 32);          // 8 ints
    float* partials = (float*)((char*)d_ws + 64);        // 1024*3 floats
    float* yG       = (float*)((char*)d_ws + 64 + 12288);// 8*3 floats

    hipMemsetAsync(d_ws, 0, 64, stream);                 // zero cnt+flag each call
    fused_leader<<<dim3(4, 32, 8), 256, 0, stream>>>(in1, in2, in3, Wd, bd, ad, Wu, bu, au,
                                                     Wc, bc, ag, cnt, flag, partials, yG, out);
}

// Round 11
// 91.035 us; speedup vs baseline: 1.5197x; 1.3857x over previous
//
#include <hip/hip_runtime.h>

#define HW 512
#define PITCH 408   // d1 LDS row pitch (dwords); off(c) = 3c + (c>>3), max 402 < 408

__device__ __forceinline__ float prelu(float x, float a) { return x >= 0.f ? x : a * x; }

#define AGENT __HIP_MEMORY_SCOPE_AGENT

// Single fused kernel; cross-block sync done ENTIRELY with RMW atomics (coherent at
// MALL on multi-XCD gfx950 — plain atomic loads can be served stale from the local
// non-coherent XCD L2, which is the 125us pathology of rounds 4/9/10).
// Grid (4,32,8) = 1024 blocks = 4/CU (LDS 28KB, VGPR<=128) -> all co-resident.
// Leader (last block of its batch) reduces 128 partials in a fixed tree (bitwise-
// deterministic y), publishes y to 32 replicated lines; others poll via 0-RMW.
__global__ __launch_bounds__(256, 4) void fused_rmw(
    const float* __restrict__ in1, const float* __restrict__ in2, const float* __restrict__ in3,
    const float* __restrict__ Wd, const float* __restrict__ bd, const float* __restrict__ ad,
    const float* __restrict__ Wu, const float* __restrict__ bu, const float* __restrict__ au,
    const float* __restrict__ Wc, const float* __restrict__ bc, const float* __restrict__ ag,
    int* __restrict__ cnt, unsigned int* __restrict__ yrep, float* __restrict__ partials,
    float* __restrict__ out)
{
    __shared__ float d1[17 * PITCH];
    __shared__ float red[4][3];
    __shared__ float ybuf[3];
    __shared__ int   leader_f;

    const int tid   = threadIdx.x;
    const int bx    = blockIdx.x;      // 0..3  col tile (128 px)
    const int by    = blockIdx.y;      // 0..31 row tile (16 px)
    const int batch = blockIdx.z;      // 0..7
    const int h0    = by * 16;
    const int w0b   = bx * 128;

    float wd[9], wu[9];
    #pragma unroll
    for (int k = 0; k < 9; k++) { wd[k] = Wd[k]; wu[k] = Wu[k]; }
    const float bd0 = bd[0], bd1 = bd[1], bd2 = bd[2];
    const float ad0 = ad[0], ad1 = ad[1], ad2 = ad[2];
    const float bu0 = bu[0], bu1 = bu[1], bu2 = bu[2];
    const float au0 = au[0], au1 = au[1], au2 = au[2];
    const float cu0 = prelu(bu0, au0), cu1 = prelu(bu1, au1), cu2 = prelu(bu2, au2);

    // ---- Phase A: stage d1 (17 rows x 129 cols), branch-free aligned float4 loads ----
    #pragma unroll
    for (int step = 0; step < 2; ++step) {
        const int r = step ? 16 : (tid >> 4);
        const int g = step ? tid : (tid & 15);
        if (step == 0 || tid < 16) {
            const int gh  = h0 + r;
            const int ghc = gh < HW ? gh : (HW - 1);
            const float* rb = in1 + ((size_t)(batch * 1024 + 2 * ghc)) * 3072;
            const int px0 = 2 * w0b + 16 * g;
            const float4* lp = reinterpret_cast<const float4*>(rb + (size_t)px0 * 3);
            float arr[52];
            #pragma unroll
            for (int k = 0; k < 13; ++k)
                *reinterpret_cast<float4*>(&arr[4 * k]) = lp[k];

            const bool rowOOR = (gh >= HW);
            float* q = d1 + r * PITCH + 25 * g;   // off(8g+j) = 25g + 3j
            #pragma unroll
            for (int j = 0; j < 8; ++j) {
                const float x0 = arr[6 * j], x1 = arr[6 * j + 1], x2 = arr[6 * j + 2];
                float v0 = prelu(x0 * wd[0] + x1 * wd[3] + x2 * wd[6] + bd0, ad0);
                float v1 = prelu(x0 * wd[1] + x1 * wd[4] + x2 * wd[7] + bd1, ad1);
                float v2 = prelu(x0 * wd[2] + x1 * wd[5] + x2 * wd[8] + bd2, ad2);
                q[3 * j + 0] = rowOOR ? -INFINITY : v0;
                q[3 * j + 1] = rowOOR ? -INFINITY : v1;
                q[3 * j + 2] = rowOOR ? -INFINITY : v2;
            }
            if (g == 15) {   // halo col 128; off(128)=400
                const float x0 = arr[48], x1 = arr[49], x2 = arr[50];
                float v0 = prelu(x0 * wd[0] + x1 * wd[3] + x2 * wd[6] + bd0, ad0);
                float v1 = prelu(x0 * wd[1] + x1 * wd[4] + x2 * wd[7] + bd1, ad1);
                float v2 = prelu(x0 * wd[2] + x1 * wd[5] + x2 * wd[8] + bd2, ad2);
                const bool oor = rowOOR || (w0b + 128 >= HW);
                float* qh = d1 + r * PITCH + 400;
                qh[0] = oor ? -INFINITY : v0;
                qh[1] = oor ? -INFINITY : v1;
                qh[2] = oor ? -INFINITY : v2;
            }
        }
    }
    __syncthreads();

    // ---- Phase B: 8 consecutive px per thread ----
    const int r  = tid >> 4;
    const int g  = tid & 15;
    const int h  = h0 + r;
    const int w0 = w0b + g * 8;

    const float* in2p = in2 + ((size_t)((batch * HW + h) * HW + w0)) * 3;
    float i2v[24];
    #pragma unroll
    for (int k = 0; k < 6; ++k)
        *reinterpret_cast<float4*>(&i2v[4 * k]) = reinterpret_cast<const float4*>(in2p)[k];

    const int he   = h + (h & 1);
    const bool rOK = he < HW;
    const int hr3  = rOK ? (he >> 1) : 255;
    const int w3   = w0 >> 1;
    float ur[15];
    #pragma unroll
    for (int k = 0; k < 5; ++k) {
        const int wc = (w3 + k < 256) ? (w3 + k) : 255;
        const float* p = in3 + ((size_t)(batch * 256 + hr3) * 256 + wc) * 3;
        ur[3 * k + 0] = p[0]; ur[3 * k + 1] = p[1]; ur[3 * k + 2] = p[2];
    }
    float ud[5][3];
    #pragma unroll
    for (int k = 0; k < 5; ++k) {
        const bool ok = rOK && (w3 + k < 256);
        const float x0 = ur[3 * k], x1 = ur[3 * k + 1], x2 = ur[3 * k + 2];
        const float u0 = prelu(x0 * wu[0] + x1 * wu[3] + x2 * wu[6] + bu0, au0);
        const float u1 = prelu(x0 * wu[1] + x1 * wu[4] + x2 * wu[7] + bu1, au1);
        const float u2 = prelu(x0 * wu[2] + x1 * wu[5] + x2 * wu[8] + bu2, au2);
        ud[k][0] = ok ? fmaxf(cu0, u0) : cu0;
        ud[k][1] = ok ? fmaxf(cu1, u1) : cu1;
        ud[k][2] = ok ? fmaxf(cu2, u2) : cu2;
    }

    const int baseA = r * PITCH + 25 * g;
    const int baseB = baseA + PITCH;
    float pA0 = d1[baseA + 0], pA1 = d1[baseA + 1], pA2 = d1[baseA + 2];
    float pB0 = d1[baseB + 0], pB1 = d1[baseB + 1], pB2 = d1[baseB + 2];

    float s[8][3];
    #pragma unroll
    for (int j = 0; j < 8; ++j) {
        const int o = 3 * (j + 1) + ((j + 1) >> 3);
        const float cA0 = d1[baseA + o], cA1 = d1[baseA + o + 1], cA2 = d1[baseA + o + 2];
        const float cB0 = d1[baseB + o], cB1 = d1[baseB + o + 1], cB2 = d1[baseB + o + 2];
        const int uk = (j + 1) >> 1;
        s[j][0] = fmaxf(fmaxf(pA0, cA0), fmaxf(pB0, cB0)) + i2v[3 * j + 0] + ud[uk][0];
        s[j][1] = fmaxf(fmaxf(pA1, cA1), fmaxf(pB1, cB1)) + i2v[3 * j + 1] + ud[uk][1];
        s[j][2] = fmaxf(fmaxf(pA2, cA2), fmaxf(pB2, cB2)) + i2v[3 * j + 2] + ud[uk][2];
        pA0 = cA0; pA1 = cA1; pA2 = cA2;
        pB0 = cB0; pB1 = cB1; pB2 = cB2;
    }

    // ---- block partial + publish + leader election ----
    float sum0 = 0.f, sum1 = 0.f, sum2 = 0.f;
    #pragma unroll
    for (int j = 0; j < 8; ++j) { sum0 += s[j][0]; sum1 += s[j][1]; sum2 += s[j][2]; }
    #pragma unroll
    for (int off = 32; off > 0; off >>= 1) {
        sum0 += __shfl_down(sum0, off);
        sum1 += __shfl_down(sum1, off);
        sum2 += __shfl_down(sum2, off);
    }
    if ((tid & 63) == 0) { red[tid >> 6][0] = sum0; red[tid >> 6][1] = sum1; red[tid >> 6][2] = sum2; }
    __syncthreads();
    if (tid == 0) {
        const int slot = batch * 128 + by * 4 + bx;
        const float t0 = red[0][0] + red[1][0] + red[2][0] + red[3][0];
        const float t1 = red[0][1] + red[1][1] + red[2][1] + red[3][1];
        const float t2 = red[0][2] + red[1][2] + red[2][2] + red[3][2];
        __hip_atomic_store(&partials[slot * 3 + 0], t0, __ATOMIC_RELAXED, AGENT);
        __hip_atomic_store(&partials[slot * 3 + 1], t1, __ATOMIC_RELAXED, AGENT);
        __hip_atomic_store(&partials[slot * 3 + 2], t2, __ATOMIC_RELAXED, AGENT);
        const int old = __hip_atomic_fetch_add(&cnt[batch], 1, __ATOMIC_ACQ_REL, AGENT);
        leader_f = (old == 127);
    }
    __syncthreads();

    if (leader_f) {
        // leader: RMW-read all 128 partials (always coherent), fixed-tree reduce
        if (tid < 64) {
            float* pw = partials + batch * 128 * 3;
            const int i0 = tid * 3, i1 = (tid + 64) * 3;
            float g0 = __hip_atomic_fetch_add(&pw[i0 + 0], 0.f, __ATOMIC_RELAXED, AGENT)
                     + __hip_atomic_fetch_add(&pw[i1 + 0], 0.f, __ATOMIC_RELAXED, AGENT);
            float g1 = __hip_atomic_fetch_add(&pw[i0 + 1], 0.f, __ATOMIC_RELAXED, AGENT)
                     + __hip_atomic_fetch_add(&pw[i1 + 1], 0.f, __ATOMIC_RELAXED, AGENT);
            float g2 = __hip_atomic_fetch_add(&pw[i0 + 2], 0.f, __ATOMIC_RELAXED, AGENT)
                     + __hip_atomic_fetch_add(&pw[i1 + 2], 0.f, __ATOMIC_RELAXED, AGENT);
            #pragma unroll
            for (int off = 32; off > 0; off >>= 1) {
                g0 += __shfl_down(g0, off);
                g1 += __shfl_down(g1, off);
                g2 += __shfl_down(g2, off);
            }
            if (tid == 0) {
                const float inv_n = 1.f / (float)(HW * HW);
                g0 *= inv_n; g1 *= inv_n; g2 *= inv_n;
                const float x0 = prelu(g0 * Wc[0] + g1 * Wc[3] + g2 * Wc[6] + bc[0], ag[0]);
                const float x1 = prelu(g0 * Wc[1] + g1 * Wc[4] + g2 * Wc[7] + bc[1], ag[1]);
                const float x2 = prelu(g0 * Wc[2] + g1 * Wc[5] + g2 * Wc[8] + bc[2], ag[2]);
                const float q0 = x0 * Wc[0] + x1 * Wc[3] + x2 * Wc[6] + bc[0];
                const float q1 = x0 * Wc[1] + x1 * Wc[4] + x2 * Wc[7] + bc[1];
                const float q2 = x0 * Wc[2] + x1 * Wc[5] + x2 * Wc[8] + bc[2];
                const float m  = fmaxf(q0, fmaxf(q1, q2));
                const float e0 = expf(q0 - m), e1 = expf(q1 - m), e2 = expf(q2 - m);
                const float inv = 1.f / (e0 + e1 + e2);
                ybuf[0] = e0 * inv; ybuf[1] = e1 * inv; ybuf[2] = e2 * inv;
            }
        }
        __syncthreads();   // publish ybuf to whole leader block
        if (tid < 32) {    // 32 replicated 16B lines per batch; valid word via RELEASE RMW
            unsigned int* rep = yrep + (batch * 32 + tid) * 4;
            __hip_atomic_store(&rep[0], __float_as_uint(ybuf[0]), __ATOMIC_RELAXED, AGENT);
            __hip_atomic_store(&rep[1], __float_as_uint(ybuf[1]), __ATOMIC_RELAXED, AGENT);
            __hip_atomic_store(&rep[2], __float_as_uint(ybuf[2]), __ATOMIC_RELAXED, AGENT);
            __hip_atomic_fetch_add(&rep[3], 1u, __ATOMIC_RELEASE, AGENT);
        }
    } else {
        // non-leader: one lane polls its replica's valid word with a 0-RMW (coherent)
        if (tid == 0) {
            unsigned int* rep = yrep + (batch * 32 + ((by * 4 + bx) & 31)) * 4;
            while (__hip_atomic_fetch_add(&rep[3], 0u, __ATOMIC_ACQUIRE, AGENT) == 0)
                __builtin_amdgcn_s_sleep(64);
            ybuf[0] = __uint_as_float(__hip_atomic_fetch_add(&rep[0], 0u, __ATOMIC_RELAXED, AGENT));
            ybuf[1] = __uint_as_float(__hip_atomic_fetch_add(&rep[1], 0u, __ATOMIC_RELAXED, AGENT));
            ybuf[2] = __uint_as_float(__hip_atomic_fetch_add(&rep[2], 0u, __ATOMIC_RELAXED, AGENT));
        }
    }
    __syncthreads();
    const float ym[3] = { ybuf[0], ybuf[1], ybuf[2] };

    // ---- scale register-resident s, write 6x float4 ----
    float* outp = out + ((size_t)((batch * HW + h) * HW + w0)) * 3;
    #pragma unroll
    for (int k = 0; k < 6; ++k) {
        float4 v;
        v.x = s[(4 * k + 0) / 3][(4 * k + 0) % 3] * ym[(4 * k + 0) % 3];
        v.y = s[(4 * k + 1) / 3][(4 * k + 1) % 3] * ym[(4 * k + 1) % 3];
        v.z = s[(4 * k + 2) / 3][(4 * k + 2) % 3] * ym[(4 * k + 2) % 3];
        v.w = s[(4 * k + 3) / 3][(4 * k + 3) % 3] * ym[(4 * k + 3) % 3];
        reinterpret_cast<float4*>(outp)[k] = v;
    }
}

extern "C" void kernel_launch(void* const* d_in, const int* in_sizes, int n_in,
                              void* d_out, int out_size, void* d_ws, size_t ws_size,
                              hipStream_t stream)
{
    const float* in1 = (const float*)d_in[0];
    const float* in2 = (const float*)d_in[1];
    const float* in3 = (const float*)d_in[2];
    const float* Wd  = (const float*)d_in[3];
    const float* bd  = (const float*)d_in[4];
    const float* ad  = (const float*)d_in[5];
    const float* Wu  = (const float*)d_in[6];
    const float* bu  = (const float*)d_in[7];
    const float* au  = (const float*)d_in[8];
    const float* Wc  = (const float*)d_in[9];
    const float* bc  = (const float*)d_in[10];
    const float* ag  = (const float*)d_in[11];
    float* out = (float*)d_out;

    int*          cnt      = (int*)d_ws;                          // 8 ints (64B region)
    unsigned int* yrep     = (unsigned int*)((char*)d_ws + 64);   // 8*32*4 uints = 4096B
    float*        partials = (float*)((char*)d_ws + 64 + 4096);   // 1024*3 floats

    hipMemsetAsync(d_ws, 0, 64 + 4096, stream);   // zero cnt + yrep valid words each call
    fused_rmw<<<dim3(4, 32, 8), 256, 0, stream>>>(in1, in2, in3, Wd, bd, ad, Wu, bu, au,
                                                  Wc, bc, ag, cnt, yrep, partials, out);
}

// Round 12
// 65.849 us; speedup vs baseline: 2.1010x; 1.3825x over previous
//
#include <hip/hip_runtime.h>

#define HW 512
#define PITCH 408   // d1 LDS row pitch (dwords); off(c) = 3c + (c>>3), max 402 < 408

__device__ __forceinline__ float prelu(float x, float a) { return x >= 0.f ? x : a * x; }

#define AGENT __HIP_MEMORY_SCOPE_AGENT

// Single fused kernel. Sync design (round-12):
//  - all cross-block READS are RMW atomics (serviced at the MALL coherence point;
//    immune to stale non-coherent XCD L2 copies — round 10's 125us pathology),
//  - spinner side uses ONLY RELAXED ordering (agent-ACQUIRE emits a full local-L2
//    invalidate on gfx9xx multi-XCD; polling with it was round 11's 70us storm),
//  - producer side carries the ordering: each block's cnt fetch_add(ACQ_REL) flushes
//    its partials before the count lands; leader's rep[3] fetch_add(RELEASE) flushes
//    y before the valid flag lands. Poll backoff s_sleep(127) ~3.4us.
// Grid (4,32,8) = 1024 blocks = 4/CU (LDS 28KB, VGPR 44) -> all co-resident.
__global__ __launch_bounds__(256, 4) void fused_rmw2(
    const float* __restrict__ in1, const float* __restrict__ in2, const float* __restrict__ in3,
    const float* __restrict__ Wd, const float* __restrict__ bd, const float* __restrict__ ad,
    const float* __restrict__ Wu, const float* __restrict__ bu, const float* __restrict__ au,
    const float* __restrict__ Wc, const float* __restrict__ bc, const float* __restrict__ ag,
    int* __restrict__ cnt, unsigned int* __restrict__ yrep, float* __restrict__ partials,
    float* __restrict__ out)
{
    __shared__ float d1[17 * PITCH];
    __shared__ float red[4][3];
    __shared__ float ybuf[3];
    __shared__ int   leader_f;

    const int tid   = threadIdx.x;
    const int bx    = blockIdx.x;      // 0..3  col tile (128 px)
    const int by    = blockIdx.y;      // 0..31 row tile (16 px)
    const int batch = blockIdx.z;      // 0..7
    const int h0    = by * 16;
    const int w0b   = bx * 128;

    float wd[9], wu[9];
    #pragma unroll
    for (int k = 0; k < 9; k++) { wd[k] = Wd[k]; wu[k] = Wu[k]; }
    const float bd0 = bd[0], bd1 = bd[1], bd2 = bd[2];
    const float ad0 = ad[0], ad1 = ad[1], ad2 = ad[2];
    const float bu0 = bu[0], bu1 = bu[1], bu2 = bu[2];
    const float au0 = au[0], au1 = au[1], au2 = au[2];
    const float cu0 = prelu(bu0, au0), cu1 = prelu(bu1, au1), cu2 = prelu(bu2, au2);

    // ---- Phase A: stage d1 (17 rows x 129 cols), branch-free aligned float4 loads ----
    #pragma unroll
    for (int step = 0; step < 2; ++step) {
        const int r = step ? 16 : (tid >> 4);
        const int g = step ? tid : (tid & 15);
        if (step == 0 || tid < 16) {
            const int gh  = h0 + r;
            const int ghc = gh < HW ? gh : (HW - 1);
            const float* rb = in1 + ((size_t)(batch * 1024 + 2 * ghc)) * 3072;
            const int px0 = 2 * w0b + 16 * g;
            const float4* lp = reinterpret_cast<const float4*>(rb + (size_t)px0 * 3);
            float arr[52];
            #pragma unroll
            for (int k = 0; k < 13; ++k)
                *reinterpret_cast<float4*>(&arr[4 * k]) = lp[k];

            const bool rowOOR = (gh >= HW);
            float* q = d1 + r * PITCH + 25 * g;   // off(8g+j) = 25g + 3j
            #pragma unroll
            for (int j = 0; j < 8; ++j) {
                const float x0 = arr[6 * j], x1 = arr[6 * j + 1], x2 = arr[6 * j + 2];
                float v0 = prelu(x0 * wd[0] + x1 * wd[3] + x2 * wd[6] + bd0, ad0);
                float v1 = prelu(x0 * wd[1] + x1 * wd[4] + x2 * wd[7] + bd1, ad1);
                float v2 = prelu(x0 * wd[2] + x1 * wd[5] + x2 * wd[8] + bd2, ad2);
                q[3 * j + 0] = rowOOR ? -INFINITY : v0;
                q[3 * j + 1] = rowOOR ? -INFINITY : v1;
                q[3 * j + 2] = rowOOR ? -INFINITY : v2;
            }
            if (g == 15) {   // halo col 128; off(128)=400
                const float x0 = arr[48], x1 = arr[49], x2 = arr[50];
                float v0 = prelu(x0 * wd[0] + x1 * wd[3] + x2 * wd[6] + bd0, ad0);
                float v1 = prelu(x0 * wd[1] + x1 * wd[4] + x2 * wd[7] + bd1, ad1);
                float v2 = prelu(x0 * wd[2] + x1 * wd[5] + x2 * wd[8] + bd2, ad2);
                const bool oor = rowOOR || (w0b + 128 >= HW);
                float* qh = d1 + r * PITCH + 400;
                qh[0] = oor ? -INFINITY : v0;
                qh[1] = oor ? -INFINITY : v1;
                qh[2] = oor ? -INFINITY : v2;
            }
        }
    }
    __syncthreads();

    // ---- Phase B: 8 consecutive px per thread ----
    const int r  = tid >> 4;
    const int g  = tid & 15;
    const int h  = h0 + r;
    const int w0 = w0b + g * 8;

    const float* in2p = in2 + ((size_t)((batch * HW + h) * HW + w0)) * 3;
    float i2v[24];
    #pragma unroll
    for (int k = 0; k < 6; ++k)
        *reinterpret_cast<float4*>(&i2v[4 * k]) = reinterpret_cast<const float4*>(in2p)[k];

    const int he   = h + (h & 1);
    const bool rOK = he < HW;
    const int hr3  = rOK ? (he >> 1) : 255;
    const int w3   = w0 >> 1;
    float ur[15];
    #pragma unroll
    for (int k = 0; k < 5; ++k) {
        const int wc = (w3 + k < 256) ? (w3 + k) : 255;
        const float* p = in3 + ((size_t)(batch * 256 + hr3) * 256 + wc) * 3;
        ur[3 * k + 0] = p[0]; ur[3 * k + 1] = p[1]; ur[3 * k + 2] = p[2];
    }
    float ud[5][3];
    #pragma unroll
    for (int k = 0; k < 5; ++k) {
        const bool ok = rOK && (w3 + k < 256);
        const float x0 = ur[3 * k], x1 = ur[3 * k + 1], x2 = ur[3 * k + 2];
        const float u0 = prelu(x0 * wu[0] + x1 * wu[3] + x2 * wu[6] + bu0, au0);
        const float u1 = prelu(x0 * wu[1] + x1 * wu[4] + x2 * wu[7] + bu1, au1);
        const float u2 = prelu(x0 * wu[2] + x1 * wu[5] + x2 * wu[8] + bu2, au2);
        ud[k][0] = ok ? fmaxf(cu0, u0) : cu0;
        ud[k][1] = ok ? fmaxf(cu1, u1) : cu1;
        ud[k][2] = ok ? fmaxf(cu2, u2) : cu2;
    }

    const int baseA = r * PITCH + 25 * g;
    const int baseB = baseA + PITCH;
    float pA0 = d1[baseA + 0], pA1 = d1[baseA + 1], pA2 = d1[baseA + 2];
    float pB0 = d1[baseB + 0], pB1 = d1[baseB + 1], pB2 = d1[baseB + 2];

    float s[8][3];
    #pragma unroll
    for (int j = 0; j < 8; ++j) {
        const int o = 3 * (j + 1) + ((j + 1) >> 3);
        const float cA0 = d1[baseA + o], cA1 = d1[baseA + o + 1], cA2 = d1[baseA + o + 2];
        const float cB0 = d1[baseB + o], cB1 = d1[baseB + o + 1], cB2 = d1[baseB + o + 2];
        const int uk = (j + 1) >> 1;
        s[j][0] = fmaxf(fmaxf(pA0, cA0), fmaxf(pB0, cB0)) + i2v[3 * j + 0] + ud[uk][0];
        s[j][1] = fmaxf(fmaxf(pA1, cA1), fmaxf(pB1, cB1)) + i2v[3 * j + 1] + ud[uk][1];
        s[j][2] = fmaxf(fmaxf(pA2, cA2), fmaxf(pB2, cB2)) + i2v[3 * j + 2] + ud[uk][2];
        pA0 = cA0; pA1 = cA1; pA2 = cA2;
        pB0 = cB0; pB1 = cB1; pB2 = cB2;
    }

    // ---- block partial + publish + leader election ----
    float sum0 = 0.f, sum1 = 0.f, sum2 = 0.f;
    #pragma unroll
    for (int j = 0; j < 8; ++j) { sum0 += s[j][0]; sum1 += s[j][1]; sum2 += s[j][2]; }
    #pragma unroll
    for (int off = 32; off > 0; off >>= 1) {
        sum0 += __shfl_down(sum0, off);
        sum1 += __shfl_down(sum1, off);
        sum2 += __shfl_down(sum2, off);
    }
    if ((tid & 63) == 0) { red[tid >> 6][0] = sum0; red[tid >> 6][1] = sum1; red[tid >> 6][2] = sum2; }
    __syncthreads();
    if (tid == 0) {
        const int slot = batch * 128 + by * 4 + bx;
        const float t0 = red[0][0] + red[1][0] + red[2][0] + red[3][0];
        const float t1 = red[0][1] + red[1][1] + red[2][1] + red[3][1];
        const float t2 = red[0][2] + red[1][2] + red[2][2] + red[3][2];
        __hip_atomic_store(&partials[slot * 3 + 0], t0, __ATOMIC_RELAXED, AGENT);
        __hip_atomic_store(&partials[slot * 3 + 1], t1, __ATOMIC_RELAXED, AGENT);
        __hip_atomic_store(&partials[slot * 3 + 2], t2, __ATOMIC_RELAXED, AGENT);
        // ACQ_REL: the release half flushes this block's partials to the MALL
        // before its count lands -> leader (old==127) can safely RMW-read them all.
        const int old = __hip_atomic_fetch_add(&cnt[batch], 1, __ATOMIC_ACQ_REL, AGENT);
        leader_f = (old == 127);
    }
    __syncthreads();

    if (leader_f) {
        // leader: RMW-read all 128 partials (coherent), fixed-tree reduce -> y
        if (tid < 64) {
            float* pw = partials + batch * 128 * 3;
            const int i0 = tid * 3, i1 = (tid + 64) * 3;
            float g0 = __hip_atomic_fetch_add(&pw[i0 + 0], 0.f, __ATOMIC_RELAXED, AGENT)
                     + __hip_atomic_fetch_add(&pw[i1 + 0], 0.f, __ATOMIC_RELAXED, AGENT);
            float g1 = __hip_atomic_fetch_add(&pw[i0 + 1], 0.f, __ATOMIC_RELAXED, AGENT)
                     + __hip_atomic_fetch_add(&pw[i1 + 1], 0.f, __ATOMIC_RELAXED, AGENT);
            float g2 = __hip_atomic_fetch_add(&pw[i0 + 2], 0.f, __ATOMIC_RELAXED, AGENT)
                     + __hip_atomic_fetch_add(&pw[i1 + 2], 0.f, __ATOMIC_RELAXED, AGENT);
            #pragma unroll
            for (int off = 32; off > 0; off >>= 1) {
                g0 += __shfl_down(g0, off);
                g1 += __shfl_down(g1, off);
                g2 += __shfl_down(g2, off);
            }
            if (tid == 0) {
                const float inv_n = 1.f / (float)(HW * HW);
                g0 *= inv_n; g1 *= inv_n; g2 *= inv_n;
                const float x0 = prelu(g0 * Wc[0] + g1 * Wc[3] + g2 * Wc[6] + bc[0], ag[0]);
                const float x1 = prelu(g0 * Wc[1] + g1 * Wc[4] + g2 * Wc[7] + bc[1], ag[1]);
                const float x2 = prelu(g0 * Wc[2] + g1 * Wc[5] + g2 * Wc[8] + bc[2], ag[2]);
                const float q0 = x0 * Wc[0] + x1 * Wc[3] + x2 * Wc[6] + bc[0];
                const float q1 = x0 * Wc[1] + x1 * Wc[4] + x2 * Wc[7] + bc[1];
                const float q2 = x0 * Wc[2] + x1 * Wc[5] + x2 * Wc[8] + bc[2];
                const float m  = fmaxf(q0, fmaxf(q1, q2));
                const float e0 = expf(q0 - m), e1 = expf(q1 - m), e2 = expf(q2 - m);
                const float inv = 1.f / (e0 + e1 + e2);
                ybuf[0] = e0 * inv; ybuf[1] = e1 * inv; ybuf[2] = e2 * inv;
            }
        }
        __syncthreads();
        if (tid < 32) {    // 32 replicated 16B lines/batch; RELEASE RMW flushes y first
            unsigned int* rep = yrep + (batch * 32 + tid) * 4;
            __hip_atomic_store(&rep[0], __float_as_uint(ybuf[0]), __ATOMIC_RELAXED, AGENT);
            __hip_atomic_store(&rep[1], __float_as_uint(ybuf[1]), __ATOMIC_RELAXED, AGENT);
            __hip_atomic_store(&rep[2], __float_as_uint(ybuf[2]), __ATOMIC_RELAXED, AGENT);
            __hip_atomic_fetch_add(&rep[3], 1u, __ATOMIC_RELEASE, AGENT);
        }
    } else {
        // non-leader: one lane, RELAXED 0-RMW poll (no cache maintenance), long backoff
        if (tid == 0) {
            unsigned int* rep = yrep + (batch * 32 + ((by * 4 + bx) & 31)) * 4;
            while (__hip_atomic_fetch_add(&rep[3], 0u, __ATOMIC_RELAXED, AGENT) == 0)
                __builtin_amdgcn_s_sleep(127);
            ybuf[0] = __uint_as_float(__hip_atomic_fetch_add(&rep[0], 0u, __ATOMIC_RELAXED, AGENT));
            ybuf[1] = __uint_as_float(__hip_atomic_fetch_add(&rep[1], 0u, __ATOMIC_RELAXED, AGENT));
            ybuf[2] = __uint_as_float(__hip_atomic_fetch_add(&rep[2], 0u, __ATOMIC_RELAXED, AGENT));
        }
    }
    __syncthreads();
    const float ym[3] = { ybuf[0], ybuf[1], ybuf[2] };

    // ---- scale register-resident s, write 6x float4 ----
    float* outp = out + ((size_t)((batch * HW + h) * HW + w0)) * 3;
    #pragma unroll
    for (int k = 0; k < 6; ++k) {
        float4 v;
        v.x = s[(4 * k + 0) / 3][(4 * k + 0) % 3] * ym[(4 * k + 0) % 3];
        v.y = s[(4 * k + 1) / 3][(4 * k + 1) % 3] * ym[(4 * k + 1) % 3];
        v.z = s[(4 * k + 2) / 3][(4 * k + 2) % 3] * ym[(4 * k + 2) % 3];
        v.w = s[(4 * k + 3) / 3][(4 * k + 3) % 3] * ym[(4 * k + 3) % 3];
        reinterpret_cast<float4*>(outp)[k] = v;
    }
}

extern "C" void kernel_launch(void* const* d_in, const int* in_sizes, int n_in,
                              void* d_out, int out_size, void* d_ws, size_t ws_size,
                              hipStream_t stream)
{
    const float* in1 = (const float*)d_in[0];
    const float* in2 = (const float*)d_in[1];
    const float* in3 = (const float*)d_in[2];
    const float* Wd  = (const float*)d_in[3];
    const float* bd  = (const float*)d_in[4];
    const float* ad  = (const float*)d_in[5];
    const float* Wu  = (const float*)d_in[6];
    const float* bu  = (const float*)d_in[7];
    const float* au  = (const float*)d_in[8];
    const float* Wc  = (const float*)d_in[9];
    const float* bc  = (const float*)d_in[10];
    const float* ag  = (const float*)d_in[11];
    float* out = (float*)d_out;

    int*          cnt      = (int*)d_ws;                          // 8 ints (64B region)
    unsigned int* yrep     = (unsigned int*)((char*)d_ws + 64);   // 8*32*4 uints = 4096B
    float*        partials = (float*)((char*)d_ws + 64 + 4096);   // 1024*3 floats

    hipMemsetAsync(d_ws, 0, 64 + 4096, stream);   // zero cnt + yrep valid words each call
    fused_rmw2<<<dim3(4, 32, 8), 256, 0, stream>>>(in1, in2, in3, Wd, bd, ad, Wu, bu, au,
                                                   Wc, bc, ag, cnt, yrep, partials, out);
}

// Round 13
// 44.793 us; speedup vs baseline: 3.0886x; 1.4701x over previous
//
#include <hip/hip_runtime.h>

#define HW 512
#define PITCH 408   // d1 LDS row pitch (dwords); off(c) = 3c + (c>>3), max 402 < 408

__device__ __forceinline__ float prelu(float x, float a) { return x >= 0.f ? x : a * x; }

#define AGENT __HIP_MEMORY_SCOPE_AGENT

// Single fused kernel. Round-13 sync: ZERO cache-maintenance instructions.
//  - every cross-block datum moves via RMW atomics (serviced at the MALL coherence
//    point; immune to stale non-coherent XCD L2 copies),
//  - ordering between "publish data" and "publish flag" is a raw s_waitcnt vmcnt(0)
//    (RMWs completed at memory) instead of release fences (which emit L2
//    writeback/invalidate walks -- the 45-70us pathologies of rounds 11/12),
//  - spinners poll with RELAXED 0-RMW + s_sleep(32) backoff.
// Grid (4,32,8) = 1024 blocks = 4/CU (LDS 28KB, VGPR 44) -> all co-resident.
__global__ __launch_bounds__(256, 4) void fused_mall(
    const float* __restrict__ in1, const float* __restrict__ in2, const float* __restrict__ in3,
    const float* __restrict__ Wd, const float* __restrict__ bd, const float* __restrict__ ad,
    const float* __restrict__ Wu, const float* __restrict__ bu, const float* __restrict__ au,
    const float* __restrict__ Wc, const float* __restrict__ bc, const float* __restrict__ ag,
    int* __restrict__ cnt, float* __restrict__ yrep, float* __restrict__ partials,
    float* __restrict__ out)
{
    __shared__ float d1[17 * PITCH];
    __shared__ float red[4][3];
    __shared__ float ybuf[3];
    __shared__ int   leader_f;

    const int tid   = threadIdx.x;
    const int bx    = blockIdx.x;      // 0..3  col tile (128 px)
    const int by    = blockIdx.y;      // 0..31 row tile (16 px)
    const int batch = blockIdx.z;      // 0..7
    const int h0    = by * 16;
    const int w0b   = bx * 128;

    float wd[9], wu[9];
    #pragma unroll
    for (int k = 0; k < 9; k++) { wd[k] = Wd[k]; wu[k] = Wu[k]; }
    const float bd0 = bd[0], bd1 = bd[1], bd2 = bd[2];
    const float ad0 = ad[0], ad1 = ad[1], ad2 = ad[2];
    const float bu0 = bu[0], bu1 = bu[1], bu2 = bu[2];
    const float au0 = au[0], au1 = au[1], au2 = au[2];
    const float cu0 = prelu(bu0, au0), cu1 = prelu(bu1, au1), cu2 = prelu(bu2, au2);

    // ---- Phase A: stage d1 (17 rows x 129 cols), branch-free aligned float4 loads ----
    #pragma unroll
    for (int step = 0; step < 2; ++step) {
        const int r = step ? 16 : (tid >> 4);
        const int g = step ? tid : (tid & 15);
        if (step == 0 || tid < 16) {
            const int gh  = h0 + r;
            const int ghc = gh < HW ? gh : (HW - 1);
            const float* rb = in1 + ((size_t)(batch * 1024 + 2 * ghc)) * 3072;
            const int px0 = 2 * w0b + 16 * g;
            const float4* lp = reinterpret_cast<const float4*>(rb + (size_t)px0 * 3);
            float arr[52];
            #pragma unroll
            for (int k = 0; k < 13; ++k)
                *reinterpret_cast<float4*>(&arr[4 * k]) = lp[k];

            const bool rowOOR = (gh >= HW);
            float* q = d1 + r * PITCH + 25 * g;   // off(8g+j) = 25g + 3j
            #pragma unroll
            for (int j = 0; j < 8; ++j) {
                const float x0 = arr[6 * j], x1 = arr[6 * j + 1], x2 = arr[6 * j + 2];
                float v0 = prelu(x0 * wd[0] + x1 * wd[3] + x2 * wd[6] + bd0, ad0);
                float v1 = prelu(x0 * wd[1] + x1 * wd[4] + x2 * wd[7] + bd1, ad1);
                float v2 = prelu(x0 * wd[2] + x1 * wd[5] + x2 * wd[8] + bd2, ad2);
                q[3 * j + 0] = rowOOR ? -INFINITY : v0;
                q[3 * j + 1] = rowOOR ? -INFINITY : v1;
                q[3 * j + 2] = rowOOR ? -INFINITY : v2;
            }
            if (g == 15) {   // halo col 128; off(128)=400
                const float x0 = arr[48], x1 = arr[49], x2 = arr[50];
                float v0 = prelu(x0 * wd[0] + x1 * wd[3] + x2 * wd[6] + bd0, ad0);
                float v1 = prelu(x0 * wd[1] + x1 * wd[4] + x2 * wd[7] + bd1, ad1);
                float v2 = prelu(x0 * wd[2] + x1 * wd[5] + x2 * wd[8] + bd2, ad2);
                const bool oor = rowOOR || (w0b + 128 >= HW);
                float* qh = d1 + r * PITCH + 400;
                qh[0] = oor ? -INFINITY : v0;
                qh[1] = oor ? -INFINITY : v1;
                qh[2] = oor ? -INFINITY : v2;
            }
        }
    }
    __syncthreads();

    // ---- Phase B: 8 consecutive px per thread ----
    const int r  = tid >> 4;
    const int g  = tid & 15;
    const int h  = h0 + r;
    const int w0 = w0b + g * 8;

    const float* in2p = in2 + ((size_t)((batch * HW + h) * HW + w0)) * 3;
    float i2v[24];
    #pragma unroll
    for (int k = 0; k < 6; ++k)
        *reinterpret_cast<float4*>(&i2v[4 * k]) = reinterpret_cast<const float4*>(in2p)[k];

    const int he   = h + (h & 1);
    const bool rOK = he < HW;
    const int hr3  = rOK ? (he >> 1) : 255;
    const int w3   = w0 >> 1;
    float ur[15];
    #pragma unroll
    for (int k = 0; k < 5; ++k) {
        const int wc = (w3 + k < 256) ? (w3 + k) : 255;
        const float* p = in3 + ((size_t)(batch * 256 + hr3) * 256 + wc) * 3;
        ur[3 * k + 0] = p[0]; ur[3 * k + 1] = p[1]; ur[3 * k + 2] = p[2];
    }
    float ud[5][3];
    #pragma unroll
    for (int k = 0; k < 5; ++k) {
        const bool ok = rOK && (w3 + k < 256);
        const float x0 = ur[3 * k], x1 = ur[3 * k + 1], x2 = ur[3 * k + 2];
        const float u0 = prelu(x0 * wu[0] + x1 * wu[3] + x2 * wu[6] + bu0, au0);
        const float u1 = prelu(x0 * wu[1] + x1 * wu[4] + x2 * wu[7] + bu1, au1);
        const float u2 = prelu(x0 * wu[2] + x1 * wu[5] + x2 * wu[8] + bu2, au2);
        ud[k][0] = ok ? fmaxf(cu0, u0) : cu0;
        ud[k][1] = ok ? fmaxf(cu1, u1) : cu1;
        ud[k][2] = ok ? fmaxf(cu2, u2) : cu2;
    }

    const int baseA = r * PITCH + 25 * g;
    const int baseB = baseA + PITCH;
    float pA0 = d1[baseA + 0], pA1 = d1[baseA + 1], pA2 = d1[baseA + 2];
    float pB0 = d1[baseB + 0], pB1 = d1[baseB + 1], pB2 = d1[baseB + 2];

    float s[8][3];
    #pragma unroll
    for (int j = 0; j < 8; ++j) {
        const int o = 3 * (j + 1) + ((j + 1) >> 3);
        const float cA0 = d1[baseA + o], cA1 = d1[baseA + o + 1], cA2 = d1[baseA + o + 2];
        const float cB0 = d1[baseB + o], cB1 = d1[baseB + o + 1], cB2 = d1[baseB + o + 2];
        const int uk = (j + 1) >> 1;
        s[j][0] = fmaxf(fmaxf(pA0, cA0), fmaxf(pB0, cB0)) + i2v[3 * j + 0] + ud[uk][0];
        s[j][1] = fmaxf(fmaxf(pA1, cA1), fmaxf(pB1, cB1)) + i2v[3 * j + 1] + ud[uk][1];
        s[j][2] = fmaxf(fmaxf(pA2, cA2), fmaxf(pB2, cB2)) + i2v[3 * j + 2] + ud[uk][2];
        pA0 = cA0; pA1 = cA1; pA2 = cA2;
        pB0 = cB0; pB1 = cB1; pB2 = cB2;
    }

    // ---- block partial + RMW publish (no cache ops) + leader election ----
    float sum0 = 0.f, sum1 = 0.f, sum2 = 0.f;
    #pragma unroll
    for (int j = 0; j < 8; ++j) { sum0 += s[j][0]; sum1 += s[j][1]; sum2 += s[j][2]; }
    #pragma unroll
    for (int off = 32; off > 0; off >>= 1) {
        sum0 += __shfl_down(sum0, off);
        sum1 += __shfl_down(sum1, off);
        sum2 += __shfl_down(sum2, off);
    }
    if ((tid & 63) == 0) { red[tid >> 6][0] = sum0; red[tid >> 6][1] = sum1; red[tid >> 6][2] = sum2; }
    __syncthreads();
    if (tid == 0) {
        const int slot = batch * 128 + by * 4 + bx;
        const float t0 = red[0][0] + red[1][0] + red[2][0] + red[3][0];
        const float t1 = red[0][1] + red[1][1] + red[2][1] + red[3][1];
        const float t2 = red[0][2] + red[1][2] + red[2][2] + red[3][2];
        // publish via RMW onto zeroed slots: lands at MALL, exact value (t + 0.0)
        __hip_atomic_fetch_add(&partials[slot * 3 + 0], t0, __ATOMIC_RELAXED, AGENT);
        __hip_atomic_fetch_add(&partials[slot * 3 + 1], t1, __ATOMIC_RELAXED, AGENT);
        __hip_atomic_fetch_add(&partials[slot * 3 + 2], t2, __ATOMIC_RELAXED, AGENT);
        asm volatile("s_waitcnt vmcnt(0)" ::: "memory");   // partials at MALL before count
        const int old = __hip_atomic_fetch_add(&cnt[batch], 1, __ATOMIC_RELAXED, AGENT);
        leader_f = (old == 127);
    }
    __syncthreads();

    if (leader_f) {
        // leader: RMW-read all 128 partials (coherent at MALL), fixed-tree reduce -> y
        if (tid < 64) {
            float* pw = partials + batch * 128 * 3;
            const int i0 = tid * 3, i1 = (tid + 64) * 3;
            float g0 = __hip_atomic_fetch_add(&pw[i0 + 0], 0.f, __ATOMIC_RELAXED, AGENT)
                     + __hip_atomic_fetch_add(&pw[i1 + 0], 0.f, __ATOMIC_RELAXED, AGENT);
            float g1 = __hip_atomic_fetch_add(&pw[i0 + 1], 0.f, __ATOMIC_RELAXED, AGENT)
                     + __hip_atomic_fetch_add(&pw[i1 + 1], 0.f, __ATOMIC_RELAXED, AGENT);
            float g2 = __hip_atomic_fetch_add(&pw[i0 + 2], 0.f, __ATOMIC_RELAXED, AGENT)
                     + __hip_atomic_fetch_add(&pw[i1 + 2], 0.f, __ATOMIC_RELAXED, AGENT);
            #pragma unroll
            for (int off = 32; off > 0; off >>= 1) {
                g0 += __shfl_down(g0, off);
                g1 += __shfl_down(g1, off);
                g2 += __shfl_down(g2, off);
            }
            if (tid == 0) {
                const float inv_n = 1.f / (float)(HW * HW);
                g0 *= inv_n; g1 *= inv_n; g2 *= inv_n;
                const float x0 = prelu(g0 * Wc[0] + g1 * Wc[3] + g2 * Wc[6] + bc[0], ag[0]);
                const float x1 = prelu(g0 * Wc[1] + g1 * Wc[4] + g2 * Wc[7] + bc[1], ag[1]);
                const float x2 = prelu(g0 * Wc[2] + g1 * Wc[5] + g2 * Wc[8] + bc[2], ag[2]);
                const float q0 = x0 * Wc[0] + x1 * Wc[3] + x2 * Wc[6] + bc[0];
                const float q1 = x0 * Wc[1] + x1 * Wc[4] + x2 * Wc[7] + bc[1];
                const float q2 = x0 * Wc[2] + x1 * Wc[5] + x2 * Wc[8] + bc[2];
                const float m  = fmaxf(q0, fmaxf(q1, q2));
                const float e0 = expf(q0 - m), e1 = expf(q1 - m), e2 = expf(q2 - m);
                const float inv = 1.f / (e0 + e1 + e2);
                ybuf[0] = e0 * inv; ybuf[1] = e1 * inv; ybuf[2] = e2 * inv;
            }
        }
        __syncthreads();
        if (tid < 32) {    // 32 replicated lines/batch; RMW + vmcnt + RMW flag (no cache ops)
            float* rep = yrep + (batch * 32 + tid) * 4;
            __hip_atomic_fetch_add(&rep[0], ybuf[0], __ATOMIC_RELAXED, AGENT);
            __hip_atomic_fetch_add(&rep[1], ybuf[1], __ATOMIC_RELAXED, AGENT);
            __hip_atomic_fetch_add(&rep[2], ybuf[2], __ATOMIC_RELAXED, AGENT);
            asm volatile("s_waitcnt vmcnt(0)" ::: "memory");   // y at MALL before flag
            __hip_atomic_fetch_add(&rep[3], 1.f, __ATOMIC_RELAXED, AGENT);
        }
    } else {
        // non-leader: one lane, RELAXED 0-RMW poll (no cache maintenance)
        if (tid == 0) {
            float* rep = yrep + (batch * 32 + ((by * 4 + bx) & 31)) * 4;
            while (__hip_atomic_fetch_add(&rep[3], 0.f, __ATOMIC_RELAXED, AGENT) == 0.f)
                __builtin_amdgcn_s_sleep(32);
            ybuf[0] = __hip_atomic_fetch_add(&rep[0], 0.f, __ATOMIC_RELAXED, AGENT);
            ybuf[1] = __hip_atomic_fetch_add(&rep[1], 0.f, __ATOMIC_RELAXED, AGENT);
            ybuf[2] = __hip_atomic_fetch_add(&rep[2], 0.f, __ATOMIC_RELAXED, AGENT);
        }
    }
    __syncthreads();
    const float ym[3] = { ybuf[0], ybuf[1], ybuf[2] };

    // ---- scale register-resident s, write 6x float4 ----
    float* outp = out + ((size_t)((batch * HW + h) * HW + w0)) * 3;
    #pragma unroll
    for (int k = 0; k < 6; ++k) {
        float4 v;
        v.x = s[(4 * k + 0) / 3][(4 * k + 0) % 3] * ym[(4 * k + 0) % 3];
        v.y = s[(4 * k + 1) / 3][(4 * k + 1) % 3] * ym[(4 * k + 1) % 3];
        v.z = s[(4 * k + 2) / 3][(4 * k + 2) % 3] * ym[(4 * k + 2) % 3];
        v.w = s[(4 * k + 3) / 3][(4 * k + 3) % 3] * ym[(4 * k + 3) % 3];
        reinterpret_cast<float4*>(outp)[k] = v;
    }
}

extern "C" void kernel_launch(void* const* d_in, const int* in_sizes, int n_in,
                              void* d_out, int out_size, void* d_ws, size_t ws_size,
                              hipStream_t stream)
{
    const float* in1 = (const float*)d_in[0];
    const float* in2 = (const float*)d_in[1];
    const float* in3 = (const float*)d_in[2];
    const float* Wd  = (const float*)d_in[3];
    const float* bd  = (const float*)d_in[4];
    const float* ad  = (const float*)d_in[5];
    const float* Wu  = (const float*)d_in[6];
    const float* bu  = (const float*)d_in[7];
    const float* au  = (const float*)d_in[8];
    const float* Wc  = (const float*)d_in[9];
    const float* bc  = (const float*)d_in[10];
    const float* ag  = (const float*)d_in[11];
    float* out = (float*)d_out;

    int*   cnt      = (int*)d_ws;                          // 8 ints (64B region)
    float* yrep     = (float*)((char*)d_ws + 64);          // 8*32*4 floats = 4096B
    float* partials = (float*)((char*)d_ws + 64 + 4096);   // 1024*3 floats = 12288B

    // zero cnt + yrep + partials each call (publishes are fetch_add onto zeros)
    hipMemsetAsync(d_ws, 0, 64 + 4096 + 12288, stream);
    fused_mall<<<dim3(4, 32, 8), 256, 0, stream>>>(in1, in2, in3, Wd, bd, ad, Wu, bu, au,
                                                   Wc, bc, ag, cnt, yrep, partials, out);
}